// Round 16
// baseline (61.084 us; speedup 1.0000x reference)
//
#include <hip/hip_runtime.h>
#include <hip/hip_fp16.h>

#define NCH 24
#define KS 11
#define TH 32          // output rows per tile
#define TW 64          // output cols per tile
#define IWC 76         // LDS col stride (>= TW+10+2, mult of 4)
#define PFD 8          // register prefetch depth

typedef float f32x2 __attribute__((ext_vector_type(2)));

// Block-uniform scalar load: force value into SGPR (saves 11 VGPR for k[]).
__device__ __forceinline__ float uniform_load(const float* p) {
    return __int_as_float(__builtin_amdgcn_readfirstlane(__float_as_int(*p)));
}

// ===== conv inner: accumulate packed pairs ================================
__device__ __forceinline__ void conv_acc(
    f32x2* a01, f32x2* a23, const float* k, int ri, float xv, float yv)
{
    f32x2 vxy, vsx;
    vxy.x = xv; vxy.y = yv;
    vsx.x = fmaf(yv, yv, xv * xv);   // xx+yy
    vsx.y = xv * yv;                 // xy
#pragma unroll
    for (int rv = 0; rv < 11; ++rv) {
        if (rv < (ri > 10 ? ri - 10 : 0)) continue;   // compile-time folded
        if (rv > (ri < 10 ? ri : 10)) continue;
        const float kt = k[ri - rv];
        f32x2 kv; kv.x = kt; kv.y = kt;
        a01[rv] += kv * vxy;         // v_pk_fma_f32
        a23[rv] += kv * vsx;
    }
}

__device__ __forceinline__ void v_store(
    __half2 (*vb01)[IWC], __half2 (*vb23)[IWC], int r0, int c,
    const f32x2* a01, const f32x2* a23)
{
#pragma unroll
    for (int rv = 0; rv < 11; ++rv) {
        const int r = r0 + rv;
        if (r < TH) {
            vb01[r][c] = __floats2half2_rn(a01[rv].x, a01[rv].y);  // RNE
            vb23[r][c] = __floats2half2_rn(a23[rv].x, a23[rv].y);
        }
    }
}

// ===== scale-0 vertical pass: f32 inputs, rotating prefetch ===============
template<bool GUARD>
__device__ __forceinline__ void v_pass_f32(
    const float* __restrict__ Xp, const float* __restrict__ Yp,
    const float* __restrict__ k, int H, int W, int gx0, int gy0, int tid,
    __half2 (*vb01)[IWC], __half2 (*vb23)[IWC])
{
    if (tid < 3 * IWC) {
        const int c  = tid % IWC;
        const int rg = tid / IWC;
        const int r0 = rg * 11;
        const int gc = gx0 + c;
        const bool cok = (!GUARD) || (gc < W);

        f32x2 a01[11], a23[11];
#pragma unroll
        for (int i = 0; i < 11; ++i) { a01[i] = (f32x2){0.f,0.f}; a23[i] = (f32x2){0.f,0.f}; }

        const float* xptr = Xp + (size_t)(gy0 + r0) * W + gc;
        const float* yptr = Yp + (size_t)(gy0 + r0) * W + gc;

        float xr[PFD], yr[PFD];
#pragma unroll
        for (int i = 0; i < PFD; ++i) {
            if (GUARD) {
                const int gy = gy0 + r0 + i;
                xr[i] = 0.f; yr[i] = 0.f;
                if (cok && gy < H) { xr[i] = xptr[0]; yr[i] = yptr[0]; }
            } else {
                xr[i] = xptr[0]; yr[i] = yptr[0];
            }
            xptr += W; yptr += W;
        }

#pragma unroll
        for (int ri = 0; ri < 21; ++ri) {
            const int s = ri % PFD;
            const float xv = xr[s], yv = yr[s];
            if (ri + PFD < 21) {
                if (GUARD) {
                    const int gy = gy0 + r0 + ri + PFD;
                    xr[s] = 0.f; yr[s] = 0.f;
                    if (cok && gy < H) { xr[s] = xptr[0]; yr[s] = yptr[0]; }
                } else {
                    xr[s] = xptr[0]; yr[s] = yptr[0];
                }
                xptr += W; yptr += W;
            }
            conv_acc(a01, a23, k, ri, xv, yv);
        }
        v_store(vb01, vb23, r0, c, a01, a23);
    }
}

// ===== rest vertical pass: interleaved half2 input (one 4B load/row) ======
template<bool GUARD>
__device__ __forceinline__ void v_pass_h2(
    const __half2* __restrict__ XYp,
    const float* __restrict__ k, int H, int W, int gx0, int gy0, int tid,
    __half2 (*vb01)[IWC], __half2 (*vb23)[IWC])
{
    if (tid < 3 * IWC) {
        const int c  = tid % IWC;
        const int rg = tid / IWC;
        const int r0 = rg * 11;
        const int gc = gx0 + c;
        const bool cok = (!GUARD) || (gc < W);

        f32x2 a01[11], a23[11];
#pragma unroll
        for (int i = 0; i < 11; ++i) { a01[i] = (f32x2){0.f,0.f}; a23[i] = (f32x2){0.f,0.f}; }

        const __half2* p = XYp + (size_t)(gy0 + r0) * W + gc;

        __half2 hr[PFD];
#pragma unroll
        for (int i = 0; i < PFD; ++i) {
            if (GUARD) {
                const int gy = gy0 + r0 + i;
                hr[i] = __floats2half2_rn(0.f, 0.f);
                if (cok && gy < H) hr[i] = p[0];
            } else {
                hr[i] = p[0];
            }
            p += W;
        }

#pragma unroll
        for (int ri = 0; ri < 21; ++ri) {
            const int s = ri % PFD;
            float2 f = __half22float2(hr[s]);
            if (ri + PFD < 21) {
                if (GUARD) {
                    const int gy = gy0 + r0 + ri + PFD;
                    hr[s] = __floats2half2_rn(0.f, 0.f);
                    if (cok && gy < H) hr[s] = p[0];
                } else {
                    hr[s] = p[0];
                }
                p += W;
            }
            conv_acc(a01, a23, k, ri, f.x, f.y);
        }
        v_store(vb01, vb23, r0, c, a01, a23);
    }
}

// ===== horizontal pass: fp16x2 LDS -> f32x2 pk-conv + SSIM ================
template<bool GUARD>
__device__ __forceinline__ void h_pass_pk(
    const float* __restrict__ k, int H, int W, int gx0, int gy0, int tid,
    const __half2 (*vb01)[IWC], const __half2 (*vb23)[IWC],
    float& ss_acc, float& cs_acc)
{
    const float c1 = 1e-4f, c2 = 9e-4f;
    const int row = tid >> 3;
    const int cg  = tid & 7;
    const int c0  = cg * 8;
    const bool rowok = (!GUARD) || ((gy0 + row) <= (H - KS));

    f32x2 h01[8], h23[8];
#pragma unroll
    for (int j = 0; j < 8; ++j) { h01[j] = (f32x2){0.f,0.f}; h23[j] = (f32x2){0.f,0.f}; }

#pragma unroll
    for (int fp = 0; fp < 2; ++fp) {
        const uint4* p = reinterpret_cast<const uint4*>(
            fp == 0 ? &vb01[row][c0] : &vb23[row][c0]);
        f32x2* h2 = (fp == 0) ? h01 : h23;
#pragma unroll
        for (int b = 0; b < 5; ++b) {
            uint4 q = p[b];
            unsigned qs[4] = {q.x, q.y, q.z, q.w};
#pragma unroll
            for (int u = 0; u < 4; ++u) {
                const int i = 4 * b + u;
                if (i > 17) continue;        // w[0..17] used (j<=7, t<=10)
                __half2 hv = *reinterpret_cast<const __half2*>(&qs[u]);
                float2 f = __half22float2(hv);
                f32x2 w; w.x = f.x; w.y = f.y;
#pragma unroll
                for (int j = 0; j < 8; ++j) {
                    const int t = i - j;
                    if (t >= 0 && t < KS) {
                        f32x2 kv; kv.x = k[t]; kv.y = k[t];
                        h2[j] += kv * w;     // v_pk_fma_f32
                    }
                }
            }
        }
    }

#pragma unroll
    for (int j = 0; j < 8; ++j) {
        bool ok = rowok && ((!GUARD) || ((gx0 + c0 + j) <= (W - KS)));
        if (ok) {
            float mx = h01[j].x, my = h01[j].y;
            float S = h23[j].x, vxy = h23[j].y;
            float mxx = mx * mx, myy = my * my, mxy = mx * my;
            float msum = mxx + myy;
            float sxy = vxy - mxy, ssum = S - msum;
            float cs = (2.f * sxy + c2) * __builtin_amdgcn_rcpf(ssum + c2);
            float ssv = (2.f * mxy + c1) * __builtin_amdgcn_rcpf(msum + c1) * cs;
            ss_acc += ssv; cs_acc += cs;
        }
    }
}

__device__ __forceinline__ void block_reduce_store(
    float ss_acc, float cs_acc, int tid, float* red, float* slot)
{
    for (int off = 32; off > 0; off >>= 1) {
        ss_acc += __shfl_down(ss_acc, off);
        cs_acc += __shfl_down(cs_acc, off);
    }
    const int wave = tid >> 6;
    if ((tid & 63) == 0) { red[wave * 2] = ss_acc; red[wave * 2 + 1] = cs_acc; }
    __syncthreads();
    if (tid == 0) {
        slot[0] = red[0] + red[2] + red[4] + red[6];
        slot[1] = red[1] + red[3] + red[5] + red[7];
    }
}

// ================= scale-0: SSIM + interleaved-half2 pooled pyramid =======
// LDS = vb 19456 + pl1(h2) 2048 + pl2 1024 + pl3 256 + red 32 = 22816 B
// -> 7 blocks/CU (159.7 KB). LB(256,7): VGPR cap 72; k[] in SGPR + PFD=8
// trims usage to ~65. Spill signature: WRITE_SIZE >> 12 MB (R6/R8/R9).
__global__ __launch_bounds__(256, 7) void ssim_scale0_kernel(
    const float* __restrict__ X, const float* __restrict__ Y,
    const float* __restrict__ kern, float* __restrict__ part,
    __half2* __restrict__ XY1, __half2* __restrict__ XY2,
    __half2* __restrict__ XY3, __half2* __restrict__ XY4)
{
    const int H = 512, W = 512;
    const int nc  = blockIdx.z;
    const int ch  = nc % 3;
    const int gx0 = blockIdx.x * TW;
    const int gy0 = blockIdx.y * TH;
    const int tid = threadIdx.x;

    __shared__ __align__(16) __half2 vb01[TH][IWC];
    __shared__ __align__(16) __half2 vb23[TH][IWC];
    __shared__ __half2 pl1[512];  // lvl1 staging (16r x 32c), quantized
    __shared__ float2 pl2[128];   // lvl2 (8r x 16c) f32
    __shared__ float2 pl3[32];    // lvl3 (4r x 8c) f32
    __shared__ float red[8];

    float k[KS];
#pragma unroll
    for (int t = 0; t < KS; ++t) k[t] = uniform_load(&kern[ch * KS + t]);  // SGPR

    const float* Xp = X + (size_t)nc * H * W;
    const float* Yp = Y + (size_t)nc * H * W;

    const bool guard = (gx0 + IWC > W) || (gy0 + TH + 11 > H);
    if (guard) v_pass_f32<true >(Xp, Yp, k, H, W, gx0, gy0, tid, vb01, vb23);
    else       v_pass_f32<false>(Xp, Yp, k, H, W, gx0, gy0, tid, vb01, vb23);

    // ---- lvl1 pooling (pre-barrier, lines L2-hot): regs -> global + LDS ----
    {
        const int W2 = W >> 1;
#pragma unroll
        for (int i = 0; i < 2; ++i) {
            int p = tid + i * 256;           // 16r x 32c pooled tile
            int pr = p >> 5, pc = p & 31;
            int sr = gy0 + 2 * pr, sc = gx0 + 2 * pc;
            const float* xb = Xp + (size_t)sr * W + sc;
            const float* yb = Yp + (size_t)sr * W + sc;
            float2 xa = *reinterpret_cast<const float2*>(xb);
            float2 xc = *reinterpret_cast<const float2*>(xb + W);
            float2 ya = *reinterpret_cast<const float2*>(yb);
            float2 yc = *reinterpret_cast<const float2*>(yb + W);
            float px = 0.25f * (xa.x + xa.y + xc.x + xc.y);
            float py = 0.25f * (ya.x + ya.y + yc.x + yc.y);
            __half2 hq = __floats2half2_rn(px, py);
            pl1[p] = hq;
            size_t di = (size_t)nc * W2 * W2 + (size_t)((gy0 >> 1) + pr) * W2 + ((gx0 >> 1) + pc);
            XY1[di] = hq;
        }
    }
    __syncthreads();   // covers vb + pl1

    float ss_acc = 0.f, cs_acc = 0.f;
    if (guard) h_pass_pk<true >(k, H, W, gx0, gy0, tid, vb01, vb23, ss_acc, cs_acc);
    else       h_pass_pk<false>(k, H, W, gx0, gy0, tid, vb01, vb23, ss_acc, cs_acc);

    // ---- lvl2 from pl1 (pl1 written pre-main-barrier) ----------------------
    if (tid < 128) {
        const int W4 = W >> 2;               // 8r x 16c
        int pr = tid >> 4, pc = tid & 15;
        float2 a = __half22float2(pl1[(2*pr)*32 + 2*pc]);
        float2 b = __half22float2(pl1[(2*pr)*32 + 2*pc + 1]);
        float2 cfl = __half22float2(pl1[(2*pr+1)*32 + 2*pc]);
        float2 d = __half22float2(pl1[(2*pr+1)*32 + 2*pc + 1]);
        float vx = 0.25f * (a.x + b.x + cfl.x + d.x);
        float vy = 0.25f * (a.y + b.y + cfl.y + d.y);
        pl2[tid] = make_float2(vx, vy);
        size_t di = (size_t)nc * W4 * W4 + (size_t)((gy0 >> 2) + pr) * W4 + ((gx0 >> 2) + pc);
        XY2[di] = __floats2half2_rn(vx, vy);
    }
    __syncthreads();
    if (tid < 32) {
        const int W8 = W >> 3;               // 4r x 8c
        int pr = tid >> 3, pc = tid & 7;
        float2 a = pl2[(2*pr)*16 + 2*pc],     b = pl2[(2*pr)*16 + 2*pc + 1];
        float2 cfl = pl2[(2*pr+1)*16 + 2*pc], d = pl2[(2*pr+1)*16 + 2*pc + 1];
        float vx = 0.25f * (a.x + b.x + cfl.x + d.x);
        float vy = 0.25f * (a.y + b.y + cfl.y + d.y);
        pl3[tid] = make_float2(vx, vy);
        size_t di = (size_t)nc * W8 * W8 + (size_t)((gy0 >> 3) + pr) * W8 + ((gx0 >> 3) + pc);
        XY3[di] = __floats2half2_rn(vx, vy);
    }
    __syncthreads();
    if (tid < 8) {
        const int W16 = W >> 4;              // 2r x 4c
        int pr = tid >> 2, pc = tid & 3;
        float2 a = pl3[(2*pr)*8 + 2*pc],     b = pl3[(2*pr)*8 + 2*pc + 1];
        float2 cfl = pl3[(2*pr+1)*8 + 2*pc], d = pl3[(2*pr+1)*8 + 2*pc + 1];
        float vx = 0.25f * (a.x + b.x + cfl.x + d.x);
        float vy = 0.25f * (a.y + b.y + cfl.y + d.y);
        size_t di = (size_t)nc * W16 * W16 + (size_t)((gy0 >> 4) + pr) * W16 + ((gx0 >> 4) + pc);
        XY4[di] = __floats2half2_rn(vx, vy);
    }

    int t = blockIdx.y * gridDim.x + blockIdx.x;
    block_reduce_store(ss_acc, cs_acc, tid, red,
                       part + ((size_t)nc * (gridDim.x * gridDim.y) + t) * 2);
}

// ================= merged scales 1-4 (interleaved half2 inputs) ===========
__global__ __launch_bounds__(256, 7) void ssim_rest_kernel(
    const __half2* __restrict__ xy1, const __half2* __restrict__ xy2,
    const __half2* __restrict__ xy3, const __half2* __restrict__ xy4,
    const float* __restrict__ kern, float* __restrict__ part)
{
    const int z = blockIdx.z;
    const int tid = threadIdx.x;

    int img, bx, by, H, poff, nt, gw;
    const __half2* XYs;
    if (z < 768)       { int r = z;        img = r >> 5; int t = r & 31; bx = t & 3; by = t >> 2; H = 256; XYs = xy1; poff = 6144; nt = 32; gw = 4; }
    else if (z < 960)  { int r = z - 768;  img = r >> 3; int t = r & 7;  bx = t & 1; by = t >> 1; H = 128; XYs = xy2; poff = 7680; nt = 8;  gw = 2; }
    else if (z < 1008) { int r = z - 960;  img = r >> 1; bx = 0; by = r & 1;         H = 64;  XYs = xy3; poff = 8064; nt = 2;  gw = 1; }
    else               { img = z - 1008;   bx = 0; by = 0;                           H = 32;  XYs = xy4; poff = 8160; nt = 1;  gw = 1; }
    const int W = H;
    const int gx0 = bx * TW, gy0 = by * TH;
    const int ch = img % 3;

    __shared__ __align__(16) __half2 vb01[TH][IWC];
    __shared__ __align__(16) __half2 vb23[TH][IWC];
    __shared__ float red[8];

    float k[KS];
#pragma unroll
    for (int t = 0; t < KS; ++t) k[t] = uniform_load(&kern[ch * KS + t]);  // SGPR

    const __half2* XYp = XYs + (size_t)img * H * W;

    const bool guard = (gx0 + IWC > W) || (gy0 + TH + 11 > H);
    if (guard) v_pass_h2<true >(XYp, k, H, W, gx0, gy0, tid, vb01, vb23);
    else       v_pass_h2<false>(XYp, k, H, W, gx0, gy0, tid, vb01, vb23);
    __syncthreads();

    float ss_acc = 0.f, cs_acc = 0.f;
    if (guard) h_pass_pk<true >(k, H, W, gx0, gy0, tid, vb01, vb23, ss_acc, cs_acc);
    else       h_pass_pk<false>(k, H, W, gx0, gy0, tid, vb01, vb23, ss_acc, cs_acc);

    int tl = by * gw + bx;
    block_reduce_store(ss_acc, cs_acc, tid, red,
                       part + poff + ((size_t)img * nt + tl) * 2);
}

// ================= finalize ==============================================
__global__ __launch_bounds__(256) void finalize_kernel(
    const float* __restrict__ part, const float* __restrict__ wts,
    float* __restrict__ out)
{
    __shared__ float smean[NCH][5];
    __shared__ float prods[NCH];
    const int ntiles[5] = {128, 32, 8, 2, 1};
    const int bases[5]  = {0, 6144, 7680, 8064, 8160};
    const float counts[5] = {252004.f, 60516.f, 13924.f, 2916.f, 484.f};
    int tid = threadIdx.x;

    for (int p = tid; p < NCH * 5; p += blockDim.x) {
        int s = p % 5, nc = p / 5;
        int nt = ntiles[s];
        const float* base = part + bases[s] + (size_t)nc * nt * 2;
        int sel = (s == 4) ? 0 : 1;   // ss for last scale, cs otherwise
        float acc = 0.f;
        for (int t = 0; t < nt; ++t) acc += base[t * 2 + sel];
        smean[nc][s] = acc / counts[s];
    }
    __syncthreads();
    if (tid < NCH) {
        float pr = 1.f;
#pragma unroll
        for (int s = 0; s < 5; ++s) {
            float v = fmaxf(smean[tid][s], 0.f);
            pr *= powf(v, wts[s]);
        }
        prods[tid] = pr;
    }
    __syncthreads();
    if (tid == 0) {
        float m = 0.f;
        for (int i = 0; i < NCH; ++i) m += prods[i];
        out[0] = m / (float)NCH;
    }
}

extern "C" void kernel_launch(void* const* d_in, const int* in_sizes, int n_in,
                              void* d_out, int out_size, void* d_ws, size_t ws_size,
                              hipStream_t stream)
{
    const float* x    = (const float*)d_in[0];
    const float* y    = (const float*)d_in[1];
    const float* kern = (const float*)d_in[2];
    const float* wts  = (const float*)d_in[3];
    float* out = (float*)d_out;
    float* ws  = (float*)d_ws;

    // workspace layout (float units; half2 = 1 float slot per pixel)
    size_t o = 0;
    __half2* xy1 = (__half2*)(ws + o); o += (size_t)NCH * 256 * 256;
    __half2* xy2 = (__half2*)(ws + o); o += (size_t)NCH * 128 * 128;
    __half2* xy3 = (__half2*)(ws + o); o += (size_t)NCH * 64 * 64;
    __half2* xy4 = (__half2*)(ws + o); o += (size_t)NCH * 32 * 32;
    float* part = ws + o;  // 8208 floats

    ssim_scale0_kernel<<<dim3(8, 16, NCH), 256, 0, stream>>>(
        x, y, kern, part, xy1, xy2, xy3, xy4);

    ssim_rest_kernel<<<dim3(1, 1, 1032), 256, 0, stream>>>(
        xy1, xy2, xy3, xy4, kern, part);

    finalize_kernel<<<1, 256, 0, stream>>>(part, wts, out);
}

// Round 17
// 56.959 us; speedup vs baseline: 1.0724x; 1.0724x over previous
//
#include <hip/hip_runtime.h>
#include <hip/hip_fp16.h>

#define NCH 24
#define KS 11
#define TH 32          // output rows per tile
#define TW 64          // output cols per tile
#define IWC 76         // LDS col stride (>= TW+10+2, mult of 4)

typedef float f32x2 __attribute__((ext_vector_type(2)));

// ===== conv inner: accumulate packed pairs ================================
__device__ __forceinline__ void conv_acc(
    f32x2* a01, f32x2* a23, const float* k, int ri, float xv, float yv)
{
    f32x2 vxy, vsx;
    vxy.x = xv; vxy.y = yv;
    vsx.x = fmaf(yv, yv, xv * xv);   // xx+yy
    vsx.y = xv * yv;                 // xy
#pragma unroll
    for (int rv = 0; rv < 11; ++rv) {
        if (rv < (ri > 10 ? ri - 10 : 0)) continue;   // compile-time folded
        if (rv > (ri < 10 ? ri : 10)) continue;
        const float kt = k[ri - rv];
        f32x2 kv; kv.x = kt; kv.y = kt;
        a01[rv] += kv * vxy;         // v_pk_fma_f32
        a23[rv] += kv * vsx;
    }
}

__device__ __forceinline__ void v_store(
    __half2 (*vb01)[IWC], __half2 (*vb23)[IWC], int r0, int c,
    const f32x2* a01, const f32x2* a23)
{
#pragma unroll
    for (int rv = 0; rv < 11; ++rv) {
        const int r = r0 + rv;
        if (r < TH) {
            vb01[r][c] = __floats2half2_rn(a01[rv].x, a01[rv].y);  // RNE
            vb23[r][c] = __floats2half2_rn(a23[rv].x, a23[rv].y);
        }
    }
}

// ===== scale-0 vertical pass: f32 inputs, 10-deep rotating prefetch =======
template<bool GUARD>
__device__ __forceinline__ void v_pass_f32(
    const float* __restrict__ Xp, const float* __restrict__ Yp,
    const float* __restrict__ k, int H, int W, int gx0, int gy0, int tid,
    __half2 (*vb01)[IWC], __half2 (*vb23)[IWC])
{
    if (tid < 3 * IWC) {
        const int c  = tid % IWC;
        const int rg = tid / IWC;
        const int r0 = rg * 11;
        const int gc = gx0 + c;
        const bool cok = (!GUARD) || (gc < W);

        f32x2 a01[11], a23[11];
#pragma unroll
        for (int i = 0; i < 11; ++i) { a01[i] = (f32x2){0.f,0.f}; a23[i] = (f32x2){0.f,0.f}; }

        const float* xptr = Xp + (size_t)(gy0 + r0) * W + gc;
        const float* yptr = Yp + (size_t)(gy0 + r0) * W + gc;

        float xr[10], yr[10];
#pragma unroll
        for (int i = 0; i < 10; ++i) {
            if (GUARD) {
                const int gy = gy0 + r0 + i;
                xr[i] = 0.f; yr[i] = 0.f;
                if (cok && gy < H) { xr[i] = xptr[0]; yr[i] = yptr[0]; }
            } else {
                xr[i] = xptr[0]; yr[i] = yptr[0];
            }
            xptr += W; yptr += W;
        }

#pragma unroll
        for (int ri = 0; ri < 21; ++ri) {
            const int s = ri % 10;
            const float xv = xr[s], yv = yr[s];
            if (ri + 10 < 21) {
                if (GUARD) {
                    const int gy = gy0 + r0 + ri + 10;
                    xr[s] = 0.f; yr[s] = 0.f;
                    if (cok && gy < H) { xr[s] = xptr[0]; yr[s] = yptr[0]; }
                } else {
                    xr[s] = xptr[0]; yr[s] = yptr[0];
                }
                xptr += W; yptr += W;
            }
            conv_acc(a01, a23, k, ri, xv, yv);
        }
        v_store(vb01, vb23, r0, c, a01, a23);
    }
}

// ===== rest vertical pass: interleaved half2 input (one 4B load/row) ======
template<bool GUARD>
__device__ __forceinline__ void v_pass_h2(
    const __half2* __restrict__ XYp,
    const float* __restrict__ k, int H, int W, int gx0, int gy0, int tid,
    __half2 (*vb01)[IWC], __half2 (*vb23)[IWC])
{
    if (tid < 3 * IWC) {
        const int c  = tid % IWC;
        const int rg = tid / IWC;
        const int r0 = rg * 11;
        const int gc = gx0 + c;
        const bool cok = (!GUARD) || (gc < W);

        f32x2 a01[11], a23[11];
#pragma unroll
        for (int i = 0; i < 11; ++i) { a01[i] = (f32x2){0.f,0.f}; a23[i] = (f32x2){0.f,0.f}; }

        const __half2* p = XYp + (size_t)(gy0 + r0) * W + gc;

        __half2 hr[10];
#pragma unroll
        for (int i = 0; i < 10; ++i) {
            if (GUARD) {
                const int gy = gy0 + r0 + i;
                hr[i] = __floats2half2_rn(0.f, 0.f);
                if (cok && gy < H) hr[i] = p[0];
            } else {
                hr[i] = p[0];
            }
            p += W;
        }

#pragma unroll
        for (int ri = 0; ri < 21; ++ri) {
            const int s = ri % 10;
            float2 f = __half22float2(hr[s]);
            if (ri + 10 < 21) {
                if (GUARD) {
                    const int gy = gy0 + r0 + ri + 10;
                    hr[s] = __floats2half2_rn(0.f, 0.f);
                    if (cok && gy < H) hr[s] = p[0];
                } else {
                    hr[s] = p[0];
                }
                p += W;
            }
            conv_acc(a01, a23, k, ri, f.x, f.y);
        }
        v_store(vb01, vb23, r0, c, a01, a23);
    }
}

// ===== horizontal pass: fp16x2 LDS -> f32x2 pk-conv + SSIM ================
template<bool GUARD>
__device__ __forceinline__ void h_pass_pk(
    const float* __restrict__ k, int H, int W, int gx0, int gy0, int tid,
    const __half2 (*vb01)[IWC], const __half2 (*vb23)[IWC],
    float& ss_acc, float& cs_acc)
{
    const float c1 = 1e-4f, c2 = 9e-4f;
    const int row = tid >> 3;
    const int cg  = tid & 7;
    const int c0  = cg * 8;
    const bool rowok = (!GUARD) || ((gy0 + row) <= (H - KS));

    f32x2 h01[8], h23[8];
#pragma unroll
    for (int j = 0; j < 8; ++j) { h01[j] = (f32x2){0.f,0.f}; h23[j] = (f32x2){0.f,0.f}; }

#pragma unroll
    for (int fp = 0; fp < 2; ++fp) {
        const uint4* p = reinterpret_cast<const uint4*>(
            fp == 0 ? &vb01[row][c0] : &vb23[row][c0]);
        f32x2* h2 = (fp == 0) ? h01 : h23;
#pragma unroll
        for (int b = 0; b < 5; ++b) {
            uint4 q = p[b];
            unsigned qs[4] = {q.x, q.y, q.z, q.w};
#pragma unroll
            for (int u = 0; u < 4; ++u) {
                const int i = 4 * b + u;
                if (i > 17) continue;        // w[0..17] used (j<=7, t<=10)
                __half2 hv = *reinterpret_cast<const __half2*>(&qs[u]);
                float2 f = __half22float2(hv);
                f32x2 w; w.x = f.x; w.y = f.y;
#pragma unroll
                for (int j = 0; j < 8; ++j) {
                    const int t = i - j;
                    if (t >= 0 && t < KS) {
                        f32x2 kv; kv.x = k[t]; kv.y = k[t];
                        h2[j] += kv * w;     // v_pk_fma_f32
                    }
                }
            }
        }
    }

#pragma unroll
    for (int j = 0; j < 8; ++j) {
        bool ok = rowok && ((!GUARD) || ((gx0 + c0 + j) <= (W - KS)));
        if (ok) {
            float mx = h01[j].x, my = h01[j].y;
            float S = h23[j].x, vxy = h23[j].y;
            float mxx = mx * mx, myy = my * my, mxy = mx * my;
            float msum = mxx + myy;
            float sxy = vxy - mxy, ssum = S - msum;
            float cs = (2.f * sxy + c2) * __builtin_amdgcn_rcpf(ssum + c2);
            float ssv = (2.f * mxy + c1) * __builtin_amdgcn_rcpf(msum + c1) * cs;
            ss_acc += ssv; cs_acc += cs;
        }
    }
}

__device__ __forceinline__ void block_reduce_store(
    float ss_acc, float cs_acc, int tid, float* red, float* slot)
{
    for (int off = 32; off > 0; off >>= 1) {
        ss_acc += __shfl_down(ss_acc, off);
        cs_acc += __shfl_down(cs_acc, off);
    }
    const int wave = tid >> 6;
    if ((tid & 63) == 0) { red[wave * 2] = ss_acc; red[wave * 2 + 1] = cs_acc; }
    __syncthreads();
    if (tid == 0) {
        slot[0] = red[0] + red[2] + red[4] + red[6];
        slot[1] = red[1] + red[3] + red[5] + red[7];
    }
}

// ================= scale-0: SSIM + interleaved-half2 pooled pyramid =======
// R15 configuration (best: 56.3 us). LB(256,6), f32 pl1, no readfirstlane —
// R16 showed LB(256,7)+SGPR-forcing+PFD=8 all regress (61.1 us).
__global__ __launch_bounds__(256, 6) void ssim_scale0_kernel(
    const float* __restrict__ X, const float* __restrict__ Y,
    const float* __restrict__ kern, float* __restrict__ part,
    __half2* __restrict__ XY1, __half2* __restrict__ XY2,
    __half2* __restrict__ XY3, __half2* __restrict__ XY4)
{
    const int H = 512, W = 512;
    const int nc  = blockIdx.z;
    const int ch  = nc % 3;
    const int gx0 = blockIdx.x * TW;
    const int gy0 = blockIdx.y * TH;
    const int tid = threadIdx.x;

    __shared__ __align__(16) __half2 vb01[TH][IWC];
    __shared__ __align__(16) __half2 vb23[TH][IWC];
    __shared__ float2 pl1[512];   // f32 lvl1 staging (16r x 32c)
    __shared__ float2 pl2[128];   // lvl2 (8r x 16c)
    __shared__ float2 pl3[32];    // lvl3 (4r x 8c)
    __shared__ float red[8];

    float k[KS];
#pragma unroll
    for (int t = 0; t < KS; ++t) k[t] = kern[ch * KS + t];

    const float* Xp = X + (size_t)nc * H * W;
    const float* Yp = Y + (size_t)nc * H * W;

    const bool guard = (gx0 + IWC > W) || (gy0 + TH + 11 > H);
    if (guard) v_pass_f32<true >(Xp, Yp, k, H, W, gx0, gy0, tid, vb01, vb23);
    else       v_pass_f32<false>(Xp, Yp, k, H, W, gx0, gy0, tid, vb01, vb23);

    // ---- lvl1 pooling (pre-barrier, lines L2-hot): regs -> global + LDS ----
    {
        const int W2 = W >> 1;
#pragma unroll
        for (int i = 0; i < 2; ++i) {
            int p = tid + i * 256;           // 16r x 32c pooled tile
            int pr = p >> 5, pc = p & 31;
            int sr = gy0 + 2 * pr, sc = gx0 + 2 * pc;
            const float* xb = Xp + (size_t)sr * W + sc;
            const float* yb = Yp + (size_t)sr * W + sc;
            float2 xa = *reinterpret_cast<const float2*>(xb);
            float2 xc = *reinterpret_cast<const float2*>(xb + W);
            float2 ya = *reinterpret_cast<const float2*>(yb);
            float2 yc = *reinterpret_cast<const float2*>(yb + W);
            float px = 0.25f * (xa.x + xa.y + xc.x + xc.y);
            float py = 0.25f * (ya.x + ya.y + yc.x + yc.y);
            pl1[p] = make_float2(px, py);
            size_t di = (size_t)nc * W2 * W2 + (size_t)((gy0 >> 1) + pr) * W2 + ((gx0 >> 1) + pc);
            XY1[di] = __floats2half2_rn(px, py);
        }
    }
    __syncthreads();   // covers vb + pl1

    float ss_acc = 0.f, cs_acc = 0.f;
    if (guard) h_pass_pk<true >(k, H, W, gx0, gy0, tid, vb01, vb23, ss_acc, cs_acc);
    else       h_pass_pk<false>(k, H, W, gx0, gy0, tid, vb01, vb23, ss_acc, cs_acc);

    // ---- lvl2 from pl1 (no barrier needed: pl1 pre-main-barrier) ----------
    if (tid < 128) {
        const int W4 = W >> 2;               // 8r x 16c
        int pr = tid >> 4, pc = tid & 15;
        float2 a = pl1[(2*pr)*32 + 2*pc],     b = pl1[(2*pr)*32 + 2*pc + 1];
        float2 cfl = pl1[(2*pr+1)*32 + 2*pc], d = pl1[(2*pr+1)*32 + 2*pc + 1];
        float vx = 0.25f * (a.x + b.x + cfl.x + d.x);
        float vy = 0.25f * (a.y + b.y + cfl.y + d.y);
        pl2[tid] = make_float2(vx, vy);
        size_t di = (size_t)nc * W4 * W4 + (size_t)((gy0 >> 2) + pr) * W4 + ((gx0 >> 2) + pc);
        XY2[di] = __floats2half2_rn(vx, vy);
    }
    __syncthreads();
    if (tid < 32) {
        const int W8 = W >> 3;               // 4r x 8c
        int pr = tid >> 3, pc = tid & 7;
        float2 a = pl2[(2*pr)*16 + 2*pc],     b = pl2[(2*pr)*16 + 2*pc + 1];
        float2 cfl = pl2[(2*pr+1)*16 + 2*pc], d = pl2[(2*pr+1)*16 + 2*pc + 1];
        float vx = 0.25f * (a.x + b.x + cfl.x + d.x);
        float vy = 0.25f * (a.y + b.y + cfl.y + d.y);
        pl3[tid] = make_float2(vx, vy);
        size_t di = (size_t)nc * W8 * W8 + (size_t)((gy0 >> 3) + pr) * W8 + ((gx0 >> 3) + pc);
        XY3[di] = __floats2half2_rn(vx, vy);
    }
    __syncthreads();
    if (tid < 8) {
        const int W16 = W >> 4;              // 2r x 4c
        int pr = tid >> 2, pc = tid & 3;
        float2 a = pl3[(2*pr)*8 + 2*pc],     b = pl3[(2*pr)*8 + 2*pc + 1];
        float2 cfl = pl3[(2*pr+1)*8 + 2*pc], d = pl3[(2*pr+1)*8 + 2*pc + 1];
        float vx = 0.25f * (a.x + b.x + cfl.x + d.x);
        float vy = 0.25f * (a.y + b.y + cfl.y + d.y);
        size_t di = (size_t)nc * W16 * W16 + (size_t)((gy0 >> 4) + pr) * W16 + ((gx0 >> 4) + pc);
        XY4[di] = __floats2half2_rn(vx, vy);
    }

    int t = blockIdx.y * gridDim.x + blockIdx.x;
    block_reduce_store(ss_acc, cs_acc, tid, red,
                       part + ((size_t)nc * (gridDim.x * gridDim.y) + t) * 2);
}

// ================= merged scales 1-4 (interleaved half2 inputs) ===========
__global__ __launch_bounds__(256, 6) void ssim_rest_kernel(
    const __half2* __restrict__ xy1, const __half2* __restrict__ xy2,
    const __half2* __restrict__ xy3, const __half2* __restrict__ xy4,
    const float* __restrict__ kern, float* __restrict__ part)
{
    const int z = blockIdx.z;
    const int tid = threadIdx.x;

    int img, bx, by, H, poff, nt, gw;
    const __half2* XYs;
    if (z < 768)       { int r = z;        img = r >> 5; int t = r & 31; bx = t & 3; by = t >> 2; H = 256; XYs = xy1; poff = 6144; nt = 32; gw = 4; }
    else if (z < 960)  { int r = z - 768;  img = r >> 3; int t = r & 7;  bx = t & 1; by = t >> 1; H = 128; XYs = xy2; poff = 7680; nt = 8;  gw = 2; }
    else if (z < 1008) { int r = z - 960;  img = r >> 1; bx = 0; by = r & 1;         H = 64;  XYs = xy3; poff = 8064; nt = 2;  gw = 1; }
    else               { img = z - 1008;   bx = 0; by = 0;                           H = 32;  XYs = xy4; poff = 8160; nt = 1;  gw = 1; }
    const int W = H;
    const int gx0 = bx * TW, gy0 = by * TH;
    const int ch = img % 3;

    __shared__ __align__(16) __half2 vb01[TH][IWC];
    __shared__ __align__(16) __half2 vb23[TH][IWC];
    __shared__ float red[8];

    float k[KS];
#pragma unroll
    for (int t = 0; t < KS; ++t) k[t] = kern[ch * KS + t];

    const __half2* XYp = XYs + (size_t)img * H * W;

    const bool guard = (gx0 + IWC > W) || (gy0 + TH + 11 > H);
    if (guard) v_pass_h2<true >(XYp, k, H, W, gx0, gy0, tid, vb01, vb23);
    else       v_pass_h2<false>(XYp, k, H, W, gx0, gy0, tid, vb01, vb23);
    __syncthreads();

    float ss_acc = 0.f, cs_acc = 0.f;
    if (guard) h_pass_pk<true >(k, H, W, gx0, gy0, tid, vb01, vb23, ss_acc, cs_acc);
    else       h_pass_pk<false>(k, H, W, gx0, gy0, tid, vb01, vb23, ss_acc, cs_acc);

    int tl = by * gw + bx;
    block_reduce_store(ss_acc, cs_acc, tid, red,
                       part + poff + ((size_t)img * nt + tl) * 2);
}

// ================= finalize ==============================================
__global__ __launch_bounds__(256) void finalize_kernel(
    const float* __restrict__ part, const float* __restrict__ wts,
    float* __restrict__ out)
{
    __shared__ float smean[NCH][5];
    __shared__ float prods[NCH];
    const int ntiles[5] = {128, 32, 8, 2, 1};
    const int bases[5]  = {0, 6144, 7680, 8064, 8160};
    const float counts[5] = {252004.f, 60516.f, 13924.f, 2916.f, 484.f};
    int tid = threadIdx.x;

    for (int p = tid; p < NCH * 5; p += blockDim.x) {
        int s = p % 5, nc = p / 5;
        int nt = ntiles[s];
        const float* base = part + bases[s] + (size_t)nc * nt * 2;
        int sel = (s == 4) ? 0 : 1;   // ss for last scale, cs otherwise
        float acc = 0.f;
        for (int t = 0; t < nt; ++t) acc += base[t * 2 + sel];
        smean[nc][s] = acc / counts[s];
    }
    __syncthreads();
    if (tid < NCH) {
        float pr = 1.f;
#pragma unroll
        for (int s = 0; s < 5; ++s) {
            float v = fmaxf(smean[tid][s], 0.f);
            pr *= powf(v, wts[s]);
        }
        prods[tid] = pr;
    }
    __syncthreads();
    if (tid == 0) {
        float m = 0.f;
        for (int i = 0; i < NCH; ++i) m += prods[i];
        out[0] = m / (float)NCH;
    }
}

extern "C" void kernel_launch(void* const* d_in, const int* in_sizes, int n_in,
                              void* d_out, int out_size, void* d_ws, size_t ws_size,
                              hipStream_t stream)
{
    const float* x    = (const float*)d_in[0];
    const float* y    = (const float*)d_in[1];
    const float* kern = (const float*)d_in[2];
    const float* wts  = (const float*)d_in[3];
    float* out = (float*)d_out;
    float* ws  = (float*)d_ws;

    // workspace layout (float units; half2 = 1 float slot per pixel)
    size_t o = 0;
    __half2* xy1 = (__half2*)(ws + o); o += (size_t)NCH * 256 * 256;
    __half2* xy2 = (__half2*)(ws + o); o += (size_t)NCH * 128 * 128;
    __half2* xy3 = (__half2*)(ws + o); o += (size_t)NCH * 64 * 64;
    __half2* xy4 = (__half2*)(ws + o); o += (size_t)NCH * 32 * 32;
    float* part = ws + o;  // 8208 floats

    ssim_scale0_kernel<<<dim3(8, 16, NCH), 256, 0, stream>>>(
        x, y, kern, part, xy1, xy2, xy3, xy4);

    ssim_rest_kernel<<<dim3(1, 1, 1032), 256, 0, stream>>>(
        xy1, xy2, xy3, xy4, kern, part);

    finalize_kernel<<<1, 256, 0, stream>>>(part, wts, out);
}

// Round 18
// 56.075 us; speedup vs baseline: 1.0893x; 1.0158x over previous
//
#include <hip/hip_runtime.h>
#include <hip/hip_fp16.h>

#define NCH 24
#define KS 11
#define TH 32          // output rows per tile
#define TW 64          // output cols per tile
#define IWC 76         // LDS col stride (>= TW+10+2, mult of 4)

typedef float f32x2 __attribute__((ext_vector_type(2)));

// ===== conv inner: accumulate packed pairs ================================
__device__ __forceinline__ void conv_acc(
    f32x2* a01, f32x2* a23, const float* k, int ri, float xv, float yv)
{
    f32x2 vxy, vsx;
    vxy.x = xv; vxy.y = yv;
    vsx.x = fmaf(yv, yv, xv * xv);   // xx+yy
    vsx.y = xv * yv;                 // xy
#pragma unroll
    for (int rv = 0; rv < 11; ++rv) {
        if (rv < (ri > 10 ? ri - 10 : 0)) continue;   // compile-time folded
        if (rv > (ri < 10 ? ri : 10)) continue;
        const float kt = k[ri - rv];
        f32x2 kv; kv.x = kt; kv.y = kt;
        a01[rv] += kv * vxy;         // v_pk_fma_f32
        a23[rv] += kv * vsx;
    }
}

__device__ __forceinline__ void v_store(
    __half2 (*vb01)[IWC], __half2 (*vb23)[IWC], int r0, int c,
    const f32x2* a01, const f32x2* a23)
{
#pragma unroll
    for (int rv = 0; rv < 11; ++rv) {
        const int r = r0 + rv;
        if (r < TH) {
            vb01[r][c] = __floats2half2_rn(a01[rv].x, a01[rv].y);  // RNE
            vb23[r][c] = __floats2half2_rn(a23[rv].x, a23[rv].y);
        }
    }
}

// ===== scale-0 vertical pass: f32 inputs, 10-deep rotating prefetch =======
template<bool GUARD>
__device__ __forceinline__ void v_pass_f32(
    const float* __restrict__ Xp, const float* __restrict__ Yp,
    const float* __restrict__ k, int H, int W, int gx0, int gy0, int tid,
    __half2 (*vb01)[IWC], __half2 (*vb23)[IWC])
{
    if (tid < 3 * IWC) {
        const int c  = tid % IWC;
        const int rg = tid / IWC;
        const int r0 = rg * 11;
        const int gc = gx0 + c;
        const bool cok = (!GUARD) || (gc < W);

        f32x2 a01[11], a23[11];
#pragma unroll
        for (int i = 0; i < 11; ++i) { a01[i] = (f32x2){0.f,0.f}; a23[i] = (f32x2){0.f,0.f}; }

        const float* xptr = Xp + (size_t)(gy0 + r0) * W + gc;
        const float* yptr = Yp + (size_t)(gy0 + r0) * W + gc;

        float xr[10], yr[10];
#pragma unroll
        for (int i = 0; i < 10; ++i) {
            if (GUARD) {
                const int gy = gy0 + r0 + i;
                xr[i] = 0.f; yr[i] = 0.f;
                if (cok && gy < H) { xr[i] = xptr[0]; yr[i] = yptr[0]; }
            } else {
                xr[i] = xptr[0]; yr[i] = yptr[0];
            }
            xptr += W; yptr += W;
        }

#pragma unroll
        for (int ri = 0; ri < 21; ++ri) {
            const int s = ri % 10;
            const float xv = xr[s], yv = yr[s];
            if (ri + 10 < 21) {
                if (GUARD) {
                    const int gy = gy0 + r0 + ri + 10;
                    xr[s] = 0.f; yr[s] = 0.f;
                    if (cok && gy < H) { xr[s] = xptr[0]; yr[s] = yptr[0]; }
                } else {
                    xr[s] = xptr[0]; yr[s] = yptr[0];
                }
                xptr += W; yptr += W;
            }
            conv_acc(a01, a23, k, ri, xv, yv);
        }
        v_store(vb01, vb23, r0, c, a01, a23);
    }
}

// ===== rest vertical pass: interleaved half2 input (one 4B load/row) ======
template<bool GUARD>
__device__ __forceinline__ void v_pass_h2(
    const __half2* __restrict__ XYp,
    const float* __restrict__ k, int H, int W, int gx0, int gy0, int tid,
    __half2 (*vb01)[IWC], __half2 (*vb23)[IWC])
{
    if (tid < 3 * IWC) {
        const int c  = tid % IWC;
        const int rg = tid / IWC;
        const int r0 = rg * 11;
        const int gc = gx0 + c;
        const bool cok = (!GUARD) || (gc < W);

        f32x2 a01[11], a23[11];
#pragma unroll
        for (int i = 0; i < 11; ++i) { a01[i] = (f32x2){0.f,0.f}; a23[i] = (f32x2){0.f,0.f}; }

        const __half2* p = XYp + (size_t)(gy0 + r0) * W + gc;

        __half2 hr[10];
#pragma unroll
        for (int i = 0; i < 10; ++i) {
            if (GUARD) {
                const int gy = gy0 + r0 + i;
                hr[i] = __floats2half2_rn(0.f, 0.f);
                if (cok && gy < H) hr[i] = p[0];
            } else {
                hr[i] = p[0];
            }
            p += W;
        }

#pragma unroll
        for (int ri = 0; ri < 21; ++ri) {
            const int s = ri % 10;
            float2 f = __half22float2(hr[s]);
            if (ri + 10 < 21) {
                if (GUARD) {
                    const int gy = gy0 + r0 + ri + 10;
                    hr[s] = __floats2half2_rn(0.f, 0.f);
                    if (cok && gy < H) hr[s] = p[0];
                } else {
                    hr[s] = p[0];
                }
                p += W;
            }
            conv_acc(a01, a23, k, ri, f.x, f.y);
        }
        v_store(vb01, vb23, r0, c, a01, a23);
    }
}

// ===== horizontal pass: fp16x2 LDS -> f32x2 pk-conv + SSIM ================
template<bool GUARD>
__device__ __forceinline__ void h_pass_pk(
    const float* __restrict__ k, int H, int W, int gx0, int gy0, int tid,
    const __half2 (*vb01)[IWC], const __half2 (*vb23)[IWC],
    float& ss_acc, float& cs_acc)
{
    const float c1 = 1e-4f, c2 = 9e-4f;
    const int row = tid >> 3;
    const int cg  = tid & 7;
    const int c0  = cg * 8;
    const bool rowok = (!GUARD) || ((gy0 + row) <= (H - KS));

    f32x2 h01[8], h23[8];
#pragma unroll
    for (int j = 0; j < 8; ++j) { h01[j] = (f32x2){0.f,0.f}; h23[j] = (f32x2){0.f,0.f}; }

#pragma unroll
    for (int fp = 0; fp < 2; ++fp) {
        const uint4* p = reinterpret_cast<const uint4*>(
            fp == 0 ? &vb01[row][c0] : &vb23[row][c0]);
        f32x2* h2 = (fp == 0) ? h01 : h23;
#pragma unroll
        for (int b = 0; b < 5; ++b) {
            uint4 q = p[b];
            unsigned qs[4] = {q.x, q.y, q.z, q.w};
#pragma unroll
            for (int u = 0; u < 4; ++u) {
                const int i = 4 * b + u;
                if (i > 17) continue;        // w[0..17] used (j<=7, t<=10)
                __half2 hv = *reinterpret_cast<const __half2*>(&qs[u]);
                float2 f = __half22float2(hv);
                f32x2 w; w.x = f.x; w.y = f.y;
#pragma unroll
                for (int j = 0; j < 8; ++j) {
                    const int t = i - j;
                    if (t >= 0 && t < KS) {
                        f32x2 kv; kv.x = k[t]; kv.y = k[t];
                        h2[j] += kv * w;     // v_pk_fma_f32
                    }
                }
            }
        }
    }

#pragma unroll
    for (int j = 0; j < 8; ++j) {
        bool ok = rowok && ((!GUARD) || ((gx0 + c0 + j) <= (W - KS)));
        if (ok) {
            float mx = h01[j].x, my = h01[j].y;
            float S = h23[j].x, vxy = h23[j].y;
            float mxx = mx * mx, myy = my * my, mxy = mx * my;
            float msum = mxx + myy;
            float sxy = vxy - mxy, ssum = S - msum;
            float cs = (2.f * sxy + c2) * __builtin_amdgcn_rcpf(ssum + c2);
            float ssv = (2.f * mxy + c1) * __builtin_amdgcn_rcpf(msum + c1) * cs;
            ss_acc += ssv; cs_acc += cs;
        }
    }
}

__device__ __forceinline__ void block_reduce_store(
    float ss_acc, float cs_acc, int tid, float* red, float* slot)
{
    for (int off = 32; off > 0; off >>= 1) {
        ss_acc += __shfl_down(ss_acc, off);
        cs_acc += __shfl_down(cs_acc, off);
    }
    const int wave = tid >> 6;
    if ((tid & 63) == 0) { red[wave * 2] = ss_acc; red[wave * 2 + 1] = cs_acc; }
    __syncthreads();
    if (tid == 0) {
        slot[0] = red[0] + red[2] + red[4] + red[6];
        slot[1] = red[1] + red[3] + red[5] + red[7];
    }
}

// ================= scale-0: SSIM + interleaved-half2 pooled pyramid =======
// R15 base (best: 56.3 us) + de-barriered pyramid tail: levels 2-4 run
// entirely in wave 0 after block_reduce_store (intra-wave LDS RAW is ordered
// by the in-order per-wave LDS pipe; wave_barrier pins compiler ordering).
// Waves 1-3 retire early; 2 block barriers removed from all 3072 blocks.
__global__ __launch_bounds__(256, 6) void ssim_scale0_kernel(
    const float* __restrict__ X, const float* __restrict__ Y,
    const float* __restrict__ kern, float* __restrict__ part,
    __half2* __restrict__ XY1, __half2* __restrict__ XY2,
    __half2* __restrict__ XY3, __half2* __restrict__ XY4)
{
    const int H = 512, W = 512;
    const int nc  = blockIdx.z;
    const int ch  = nc % 3;
    const int gx0 = blockIdx.x * TW;
    const int gy0 = blockIdx.y * TH;
    const int tid = threadIdx.x;

    __shared__ __align__(16) __half2 vb01[TH][IWC];
    __shared__ __align__(16) __half2 vb23[TH][IWC];
    __shared__ float2 pl1[512];   // f32 lvl1 staging (16r x 32c)
    __shared__ float2 pl2[128];   // lvl2 (8r x 16c)
    __shared__ float red[8];

    float k[KS];
#pragma unroll
    for (int t = 0; t < KS; ++t) k[t] = kern[ch * KS + t];

    const float* Xp = X + (size_t)nc * H * W;
    const float* Yp = Y + (size_t)nc * H * W;

    const bool guard = (gx0 + IWC > W) || (gy0 + TH + 11 > H);
    if (guard) v_pass_f32<true >(Xp, Yp, k, H, W, gx0, gy0, tid, vb01, vb23);
    else       v_pass_f32<false>(Xp, Yp, k, H, W, gx0, gy0, tid, vb01, vb23);

    // ---- lvl1 pooling (pre-barrier, lines L2-hot): regs -> global + LDS ----
    {
        const int W2 = W >> 1;
#pragma unroll
        for (int i = 0; i < 2; ++i) {
            int p = tid + i * 256;           // 16r x 32c pooled tile
            int pr = p >> 5, pc = p & 31;
            int sr = gy0 + 2 * pr, sc = gx0 + 2 * pc;
            const float* xb = Xp + (size_t)sr * W + sc;
            const float* yb = Yp + (size_t)sr * W + sc;
            float2 xa = *reinterpret_cast<const float2*>(xb);
            float2 xc = *reinterpret_cast<const float2*>(xb + W);
            float2 ya = *reinterpret_cast<const float2*>(yb);
            float2 yc = *reinterpret_cast<const float2*>(yb + W);
            float px = 0.25f * (xa.x + xa.y + xc.x + xc.y);
            float py = 0.25f * (ya.x + ya.y + yc.x + yc.y);
            pl1[p] = make_float2(px, py);
            size_t di = (size_t)nc * W2 * W2 + (size_t)((gy0 >> 1) + pr) * W2 + ((gx0 >> 1) + pc);
            XY1[di] = __floats2half2_rn(px, py);
        }
    }
    __syncthreads();   // covers vb + pl1

    float ss_acc = 0.f, cs_acc = 0.f;
    if (guard) h_pass_pk<true >(k, H, W, gx0, gy0, tid, vb01, vb23, ss_acc, cs_acc);
    else       h_pass_pk<false>(k, H, W, gx0, gy0, tid, vb01, vb23, ss_acc, cs_acc);

    // ---- block reduction (contains the only remaining barrier) ------------
    int t = blockIdx.y * gridDim.x + blockIdx.x;
    block_reduce_store(ss_acc, cs_acc, tid, red,
                       part + ((size_t)nc * (gridDim.x * gridDim.y) + t) * 2);

    // ---- pyramid levels 2-4: wave 0 only, wave-synchronous (no barriers) ---
    if (tid < 64) {
        const int W4 = W >> 2;               // lvl2: 8r x 16c (2 per lane)
        float2 l2v[2];
#pragma unroll
        for (int ii = 0; ii < 2; ++ii) {
            int p = tid + ii * 64;
            int pr = p >> 4, pc = p & 15;
            float2 a = pl1[(2*pr)*32 + 2*pc],     b = pl1[(2*pr)*32 + 2*pc + 1];
            float2 cfl = pl1[(2*pr+1)*32 + 2*pc], d = pl1[(2*pr+1)*32 + 2*pc + 1];
            float vx = 0.25f * (a.x + b.x + cfl.x + d.x);
            float vy = 0.25f * (a.y + b.y + cfl.y + d.y);
            l2v[ii] = make_float2(vx, vy);
            pl2[p] = l2v[ii];
            size_t di = (size_t)nc * W4 * W4 + (size_t)((gy0 >> 2) + pr) * W4 + ((gx0 >> 2) + pc);
            XY2[di] = __floats2half2_rn(vx, vy);
        }
        __builtin_amdgcn_wave_barrier();     // pin ordering (free)

        if (tid < 32) {
            const int W8 = W >> 3;           // lvl3: 4r x 8c
            int pr = tid >> 3, pc = tid & 7;
            float2 a = pl2[(2*pr)*16 + 2*pc],     b = pl2[(2*pr)*16 + 2*pc + 1];
            float2 cfl = pl2[(2*pr+1)*16 + 2*pc], d = pl2[(2*pr+1)*16 + 2*pc + 1];
            float vx = 0.25f * (a.x + b.x + cfl.x + d.x);
            float vy = 0.25f * (a.y + b.y + cfl.y + d.y);
            pl2[64 + tid] = make_float2(vx, vy);   // lvl3 staging in pl2 tail
            size_t di = (size_t)nc * W8 * W8 + (size_t)((gy0 >> 3) + pr) * W8 + ((gx0 >> 3) + pc);
            XY3[di] = __floats2half2_rn(vx, vy);
        }
        __builtin_amdgcn_wave_barrier();

        if (tid < 8) {
            const int W16 = W >> 4;          // lvl4: 2r x 4c
            int pr = tid >> 2, pc = tid & 3;
            float2 a = pl2[64 + (2*pr)*8 + 2*pc],     b = pl2[64 + (2*pr)*8 + 2*pc + 1];
            float2 cfl = pl2[64 + (2*pr+1)*8 + 2*pc], d = pl2[64 + (2*pr+1)*8 + 2*pc + 1];
            float vx = 0.25f * (a.x + b.x + cfl.x + d.x);
            float vy = 0.25f * (a.y + b.y + cfl.y + d.y);
            size_t di = (size_t)nc * W16 * W16 + (size_t)((gy0 >> 4) + pr) * W16 + ((gx0 >> 4) + pc);
            XY4[di] = __floats2half2_rn(vx, vy);
        }
    }
}

// ================= merged scales 1-4 (interleaved half2 inputs) ===========
__global__ __launch_bounds__(256, 6) void ssim_rest_kernel(
    const __half2* __restrict__ xy1, const __half2* __restrict__ xy2,
    const __half2* __restrict__ xy3, const __half2* __restrict__ xy4,
    const float* __restrict__ kern, float* __restrict__ part)
{
    const int z = blockIdx.z;
    const int tid = threadIdx.x;

    int img, bx, by, H, poff, nt, gw;
    const __half2* XYs;
    if (z < 768)       { int r = z;        img = r >> 5; int t = r & 31; bx = t & 3; by = t >> 2; H = 256; XYs = xy1; poff = 6144; nt = 32; gw = 4; }
    else if (z < 960)  { int r = z - 768;  img = r >> 3; int t = r & 7;  bx = t & 1; by = t >> 1; H = 128; XYs = xy2; poff = 7680; nt = 8;  gw = 2; }
    else if (z < 1008) { int r = z - 960;  img = r >> 1; bx = 0; by = r & 1;         H = 64;  XYs = xy3; poff = 8064; nt = 2;  gw = 1; }
    else               { img = z - 1008;   bx = 0; by = 0;                           H = 32;  XYs = xy4; poff = 8160; nt = 1;  gw = 1; }
    const int W = H;
    const int gx0 = bx * TW, gy0 = by * TH;
    const int ch = img % 3;

    __shared__ __align__(16) __half2 vb01[TH][IWC];
    __shared__ __align__(16) __half2 vb23[TH][IWC];
    __shared__ float red[8];

    float k[KS];
#pragma unroll
    for (int t = 0; t < KS; ++t) k[t] = kern[ch * KS + t];

    const __half2* XYp = XYs + (size_t)img * H * W;

    const bool guard = (gx0 + IWC > W) || (gy0 + TH + 11 > H);
    if (guard) v_pass_h2<true >(XYp, k, H, W, gx0, gy0, tid, vb01, vb23);
    else       v_pass_h2<false>(XYp, k, H, W, gx0, gy0, tid, vb01, vb23);
    __syncthreads();

    float ss_acc = 0.f, cs_acc = 0.f;
    if (guard) h_pass_pk<true >(k, H, W, gx0, gy0, tid, vb01, vb23, ss_acc, cs_acc);
    else       h_pass_pk<false>(k, H, W, gx0, gy0, tid, vb01, vb23, ss_acc, cs_acc);

    int tl = by * gw + bx;
    block_reduce_store(ss_acc, cs_acc, tid, red,
                       part + poff + ((size_t)img * nt + tl) * 2);
}

// ================= finalize ==============================================
__global__ __launch_bounds__(256) void finalize_kernel(
    const float* __restrict__ part, const float* __restrict__ wts,
    float* __restrict__ out)
{
    __shared__ float smean[NCH][5];
    __shared__ float prods[NCH];
    const int ntiles[5] = {128, 32, 8, 2, 1};
    const int bases[5]  = {0, 6144, 7680, 8064, 8160};
    const float counts[5] = {252004.f, 60516.f, 13924.f, 2916.f, 484.f};
    int tid = threadIdx.x;

    for (int p = tid; p < NCH * 5; p += blockDim.x) {
        int s = p % 5, nc = p / 5;
        int nt = ntiles[s];
        const float* base = part + bases[s] + (size_t)nc * nt * 2;
        int sel = (s == 4) ? 0 : 1;   // ss for last scale, cs otherwise
        float acc = 0.f;
        for (int t = 0; t < nt; ++t) acc += base[t * 2 + sel];
        smean[nc][s] = acc / counts[s];
    }
    __syncthreads();
    if (tid < NCH) {
        float pr = 1.f;
#pragma unroll
        for (int s = 0; s < 5; ++s) {
            float v = fmaxf(smean[tid][s], 0.f);
            pr *= powf(v, wts[s]);
        }
        prods[tid] = pr;
    }
    __syncthreads();
    if (tid == 0) {
        float m = 0.f;
        for (int i = 0; i < NCH; ++i) m += prods[i];
        out[0] = m / (float)NCH;
    }
}

extern "C" void kernel_launch(void* const* d_in, const int* in_sizes, int n_in,
                              void* d_out, int out_size, void* d_ws, size_t ws_size,
                              hipStream_t stream)
{
    const float* x    = (const float*)d_in[0];
    const float* y    = (const float*)d_in[1];
    const float* kern = (const float*)d_in[2];
    const float* wts  = (const float*)d_in[3];
    float* out = (float*)d_out;
    float* ws  = (float*)d_ws;

    // workspace layout (float units; half2 = 1 float slot per pixel)
    size_t o = 0;
    __half2* xy1 = (__half2*)(ws + o); o += (size_t)NCH * 256 * 256;
    __half2* xy2 = (__half2*)(ws + o); o += (size_t)NCH * 128 * 128;
    __half2* xy3 = (__half2*)(ws + o); o += (size_t)NCH * 64 * 64;
    __half2* xy4 = (__half2*)(ws + o); o += (size_t)NCH * 32 * 32;
    float* part = ws + o;  // 8208 floats

    ssim_scale0_kernel<<<dim3(8, 16, NCH), 256, 0, stream>>>(
        x, y, kern, part, xy1, xy2, xy3, xy4);

    ssim_rest_kernel<<<dim3(1, 1, 1032), 256, 0, stream>>>(
        xy1, xy2, xy3, xy4, kern, part);

    finalize_kernel<<<1, 256, 0, stream>>>(part, wts, out);
}